// Round 14
// baseline (6171.164 us; speedup 1.0000x reference)
//
#include <hip/hip_runtime.h>

#define TSTEPS  2048
#define DIN     64
#define UNITS   128
#define UNFOLDS 6

// SINGLE-WAVE-PER-BATCH, barrier-free LTC. 64 blocks x 64 threads (1 wave).
// A wave is self-synchronized: no s_barrier, no fences; LDS is an in-order
// mailbox (compiler emits the lgkmcnt waits). Lane (G=lane>>2, p=lane&3)
// owns units 8G..8G+7 x K-quarter [32p,32p+32).
// Per sub-step: 4x ds_read_b128 (h packed f16, words [16p,16p+16), 2-way
// bank alias = free) -> 128 dot2 (issue-bound term, 256 cyc) -> 2-stage
// quad_perm reduce-scatter (lane ends owning adjacent units u0,u0+1,
// u0 = 8G+4*(p&1)+2*((p>>1)&1)) -> nonlin x2 -> one b32 RNE-packed write
// (64 distinct words, conflict-free). Single hbuf: DS pipe is in-order per
// wave, so read(s+1) after write(s) sees new data; no ping-pong.
// Precision profile == R11 (proven 2e-3): f16 RNE on W and h only; fp32 xp.

typedef _Float16 h16x2 __attribute__((ext_vector_type(2)));

template <int CTRL>
__device__ __forceinline__ float dpp_f(float v) {
    return __int_as_float(
        __builtin_amdgcn_mov_dpp(__float_as_int(v), CTRL, 0xF, 0xF, true));
}

// RNE pack: {f16(a) low, f16(b) high}
__device__ __forceinline__ unsigned pack_rne(float a, float b) {
    unsigned short ua = __builtin_bit_cast(unsigned short, (_Float16)a);
    unsigned short ub = __builtin_bit_cast(unsigned short, (_Float16)b);
    return (unsigned)ua | ((unsigned)ub << 16);
}

__device__ __forceinline__ float dot2(h16x2 a, h16x2 b, float c) {
#if __has_builtin(__builtin_amdgcn_fdot2)
    return __builtin_amdgcn_fdot2(a, b, c, false);
#else
    return fmaf((float)a.x, (float)b.x, fmaf((float)a.y, (float)b.y, c));
#endif
}

__global__ __launch_bounds__(64) void ltc_kernel(
    const float* __restrict__ x,      // [B,T,DIN]
    const float* __restrict__ kern,   // [DIN,UNITS]
    const float* __restrict__ rk,     // [UNITS,UNITS]
    const float* __restrict__ bias,   // [UNITS]
    const float* __restrict__ tau,    // [UNITS]
    const float* __restrict__ Avec,   // [UNITS]
    const float* __restrict__ okern,  // [UNITS,1]
    const float* __restrict__ obias,  // [1]
    float* __restrict__ out)          // [B,T,1]
{
    const int b    = blockIdx.x;
    const int lane = threadIdx.x;   // 0..63, one wave
    const int p    = lane & 3;      // K-quarter
    const int G    = lane >> 2;     // unit group: units 8G..8G+7 (G in [0,16))

    __shared__ __align__(16) unsigned hbuf[UNITS / 2];  // h as packed f16x2

    // resident recurrent weights, f16 K-pairs (RNE):
    // w2_[m][j] = ( rk[32p+2m][8G+j], rk[32p+2m+1][8G+j] ), m in [0,16)
    h16x2 w2_[16][8];
    #pragma unroll
    for (int m = 0; m < 16; ++m) {
        const float* r0 = rk + (size_t)(32 * p + 2 * m) * UNITS + 8 * G;
        const float* r1 = r0 + UNITS;
        #pragma unroll
        for (int j = 0; j < 8; ++j) {
            h16x2 v; v.x = (_Float16)r0[j]; v.y = (_Float16)r1[j];
            w2_[m][j] = v;
        }
    }
    // resident input kernel, fp32: kk_[m][j] = kern[16p+m][8G+j], m in [0,16)
    float kk_[16][8];
    #pragma unroll
    for (int m = 0; m < 16; ++m) {
        const float* r0 = kern + (size_t)(16 * p + m) * UNITS + 8 * G;
        #pragma unroll
        for (int j = 0; j < 8; ++j) kk_[m][j] = r0[j];
    }

    float bias8[8];
    #pragma unroll
    for (int j = 0; j < 8; ++j) bias8[j] = (p == 0) ? bias[8 * G + j] : 0.0f;

    // owned units after reduce-scatter: u0 (even), u0+1
    const int   u0 = 8 * G + 4 * (p & 1) + 2 * ((p >> 1) & 1);
    const float dt = 1.0f / 6.0f;
    float2 Af = *(const float2*)(Avec + u0);
    float2 Tf = *(const float2*)(tau + u0);
    float2 Of = *(const float2*)(okern + u0);
    const float dtA0 = dt * Af.x, dtA1 = dt * Af.y;
    const float cd0  = 1.0f + dt / Tf.x, cd1 = 1.0f + dt / Tf.y;
    const float cp0  = cd0 + dt, cp1 = cd1 + dt;
    const float ok0  = Of.x, ok1 = Of.y;
    const float ob   = obias[0];
    const int   waddr = 4 * G + 2 * (p & 1) + ((p >> 1) & 1);  // = u0>>1

    float h0 = 0.0f, h1 = 0.0f;
    hbuf[lane] = 0u;   // 64 words zeroed; in-order DS makes it visible

    const float* xb = x + (size_t)b * TSTEPS * DIN + 16 * p;
    float4 xr[4];
    #pragma unroll
    for (int m = 0; m < 4; ++m) xr[m] = *(const float4*)(xb + 4 * m);

    for (int t = 0; t < TSTEPS; ++t) {
        // x-projection partial, exact fp32 (valid all 6 sub-steps)
        float xp[8];
        #pragma unroll
        for (int j = 0; j < 8; ++j) xp[j] = bias8[j];
        {
            float xq[16];
            #pragma unroll
            for (int m = 0; m < 4; ++m) {
                xq[4 * m + 0] = xr[m].x; xq[4 * m + 1] = xr[m].y;
                xq[4 * m + 2] = xr[m].z; xq[4 * m + 3] = xr[m].w;
            }
            #pragma unroll
            for (int m = 0; m < 16; ++m)
                #pragma unroll
                for (int j = 0; j < 8; ++j)
                    xp[j] = fmaf(xq[m], kk_[m][j], xp[j]);
        }

        // prefetch next x row (no barriers anywhere to drain it)
        int tn = (t + 1 < TSTEPS) ? t + 1 : t;
        float4 xn[4];
        #pragma unroll
        for (int m = 0; m < 4; ++m)
            xn[m] = *(const float4*)(xb + (size_t)tn * DIN + 4 * m);

        #pragma unroll
        for (int s = 0; s < UNFOLDS; ++s) {
            // this quarter's 32 h values: words [16p,16p+16), 4x b128
            h16x2 hh[16];
            {
                const uint4* hv = (const uint4*)&hbuf[16 * p];
                *(uint4*)&hh[0]  = hv[0];
                *(uint4*)&hh[4]  = hv[1];
                *(uint4*)&hh[8]  = hv[2];
                *(uint4*)&hh[12] = hv[3];
            }

            float acc[8];
            #pragma unroll
            for (int j = 0; j < 8; ++j) acc[j] = xp[j];
            #pragma unroll
            for (int m = 0; m < 16; ++m)
                #pragma unroll
                for (int j = 0; j < 8; ++j)
                    acc[j] = dot2(hh[m], w2_[m][j], acc[j]);

            // 2-stage quad reduce-scatter -> units u0, u0+1
            const bool b0 = (p & 1) != 0;
            const bool b1 = (p & 2) != 0;
            float r_[4];
            #pragma unroll
            for (int j = 0; j < 4; ++j) {
                float keep = b0 ? acc[j + 4] : acc[j];
                float send = b0 ? acc[j] : acc[j + 4];
                r_[j] = keep + dpp_f<0xB1>(send);
            }
            float s0v, s1v;
            {
                float k0 = b1 ? r_[2] : r_[0];
                float e0 = b1 ? r_[0] : r_[2];
                s0v = k0 + dpp_f<0x4E>(e0);
                float k1 = b1 ? r_[3] : r_[1];
                float e1 = b1 ? r_[1] : r_[3];
                s1v = k1 + dpp_f<0x4E>(e1);
            }

            // gating + semi-implicit Euler, 2 units per lane
            float e0 = __expf(-s0v);
            h0 = fmaf(h0, e0, h0 + dtA0) *
                 __builtin_amdgcn_rcpf(fmaf(cd0, e0, cp0));
            float e1 = __expf(-s1v);
            h1 = fmaf(h1, e1, h1 + dtA1) *
                 __builtin_amdgcn_rcpf(fmaf(cd1, e1, cp1));

            // publish both units, RNE-packed, one b32 (64 distinct words)
            hbuf[waddr] = pack_rne(h0, h1);

            if (s == UNFOLDS - 1) {
                float q = fmaf(h0, ok0, h1 * ok1);
                q += __shfl_xor(q, 1);
                q += __shfl_xor(q, 2);
                q += __shfl_xor(q, 4);
                q += __shfl_xor(q, 8);
                q += __shfl_xor(q, 16);
                q += __shfl_xor(q, 32);
                if (lane == 0) out[(size_t)b * TSTEPS + t] = q + ob;
            }
        }

        #pragma unroll
        for (int m = 0; m < 4; ++m) xr[m] = xn[m];
    }
}

extern "C" void kernel_launch(void* const* d_in, const int* in_sizes, int n_in,
                              void* d_out, int out_size, void* d_ws, size_t ws_size,
                              hipStream_t stream) {
    const float* x     = (const float*)d_in[0];
    const float* kern  = (const float*)d_in[1];
    const float* rk    = (const float*)d_in[2];
    const float* bias  = (const float*)d_in[3];
    const float* tau   = (const float*)d_in[4];
    const float* Avec  = (const float*)d_in[5];
    const float* okern = (const float*)d_in[6];
    const float* obias = (const float*)d_in[7];
    float* out = (float*)d_out;

    ltc_kernel<<<64, 64, 0, stream>>>(
        x, kern, rk, bias, tau, Avec, okern, obias, out);
}